// Round 14
// baseline (13335.555 us; speedup 1.0000x reference)
//
#include <hip/hip_runtime.h>

#define TT   100
#define PADW 20
#define HID  128
#define CIN  64
#define COUT 64
#define ALPHA 0.2f
#define LNEPS 1e-3f

typedef _Float16 f16;
typedef __attribute__((ext_vector_type(8))) _Float16 f16x8;
typedef __attribute__((ext_vector_type(4))) float f32x4;

__device__ __forceinline__ float fsig(float x) {
  return __builtin_amdgcn_rcpf(1.f + __builtin_amdgcn_exp2f(-1.44269504089f * x));
}
__device__ __forceinline__ float ftanh(float x) {
  return 1.f - 2.f * __builtin_amdgcn_rcpf(1.f + __builtin_amdgcn_exp2f(2.88539008178f * x));
}
__device__ __forceinline__ void gload16(const void* g, void* l) {
  __builtin_amdgcn_global_load_lds((const __attribute__((address_space(1))) void*)g,
                                   (__attribute__((address_space(3))) void*)l,
                                   16, 0, 0);
}

// ---------------- Kernel A: gate conv GEMM (M=8192,N=512,K=4800) + LSTM update ----------------
// R13 (halo-in-LDS + wave-private B, zero in-loop barriers) + de-serialization:
//  (1) A halo ds_reads issued BEFORE the per-tap vmcnt(4) B-wait (A is vmcnt-independent);
//  (2) tap-stagger: wave w iterates taps in order (it + 3w) % 25 -> waves on a SIMD
//      desynchronize their read/MFMA phases (taps commute; B is wave-private).
__global__ __launch_bounds__(512, 1) void kA10(
    const f16* __restrict__ Xh, const f16* __restrict__ Xl,
    const f16* __restrict__ Hch, const f16* __restrict__ Hcl,
    f16* __restrict__ Hnh, f16* __restrict__ Hnl,
    const f16* __restrict__ Wch, const f16* __restrict__ Wcl,
    const float* __restrict__ bp, float* __restrict__ cst) {
  __shared__ __align__(16) char smem[126976];   // 60KB halo + 64KB wave-private B
  f16* haloh = (f16*)(smem);                    // 240 pixels x 64ch = 30720 B
  f16* halol = (f16*)(smem + 30720);            // 30720 B
  float* macc = (float*)smem;                   // merge area (64 KB), overlaid at end

  const int tid = threadIdx.x;
  const int l = tid & 63, w = tid >> 6;
  const int h = w & 1, ns = w >> 1;         // K-half, N-substrip (32 cols)
  // XCD-pinned decomposition: blocks dispatch round-robin over 8 XCDs (bid % 8).
  const int xcd = blockIdx.x & 7, slot = blockIdx.x >> 3;
  const int ni = xcd >> 1;                    // 2 XCDs per 128-col weight strip
  const int mi = ((xcd & 1) << 5) + slot;     // 0..63
  const int b_img = mi >> 1;                  // image index
  const int ybase = (mi & 1) * 8;             // padded-row base of this block's halo
  const int off = w * 3;                      // tap-stagger offset (0..21, <25)

  // halo staging (identical to R12/R13): LDS(pix, slot3) = src(pix, slot3 ^ (hcol&7))
  auto stageHalo = [&](int sub) {
#pragma unroll
    for (int i2 = 0; i2 < 4; ++i2) {
      const int gi = w * 4 + i2;
      if (gi < 30) {
        const int sabs = gi * 64 + l;
        const int pix = sabs >> 3, slot3 = sabs & 7;
        const int hrow = pix / 20, hcol = pix - hrow * 20;
        const int sc = slot3 ^ (hcol & 7);
        const int gp = (b_img * PADW + ybase + hrow) * PADW + hcol;
        if (sub == 0) {
          gload16(Xh + gp * CIN + sc * 8, haloh + gi * 512);
          gload16(Xl + gp * CIN + sc * 8, halol + gi * 512);
        } else {
          const int ho = (sub - 1) * 64 + sc * 8;
          gload16(Hch + gp * HID + ho, haloh + gi * 512);
          gload16(Hcl + gp * HID + ho, halol + gi * 512);
        }
      }
    }
  };

  // wave-private B stage (identical to R13): rows n = ni*128+ns*32+r, K = sub*64+h*32.
  const int nbase = (ni * 128 + ns * 32) * 192;
  const int scB = ((l & 3) ^ ((l >> 3) & 3)) * 8;
  auto stageB = [&](int bf, int tap, int sub) {  // 4 gload16 per wave
    const int base = tap * (512 * 192) + nbase + sub * 64 + h * 32 + scB;
    f16* dst = (f16*)(smem + 61440 + w * 8192 + bf * 4096);
#pragma unroll
    for (int i = 0; i < 2; ++i) {
      const int so = (i * 16 + (l >> 2)) * 192;
      gload16(Wch + base + so, dst + i * 512);
      gload16(Wcl + base + so, dst + 1024 + i * 512);
    }
  };

  f32x4 acc[8][2] = {};

  const int kc8 = h * 4 + (l >> 4);                       // canonical k-chunk (of 8 in K64)
  const int rcB = ((l >> 4) ^ (((l & 15) >> 1) & 3)) * 8; // B-priv swizzled read chunk
  const int rB0 = (l & 15) * 32;                          // fn=0 row offset (f16)
  const int rB1 = (16 + (l & 15)) * 32;                   // fn=1

  int cur = 0;
  for (int sub = 0; sub < 3; ++sub) {
    if (sub) __builtin_amdgcn_s_barrier();   // all halo readers of sub-1 done
    stageHalo(sub);
    stageB(cur, off, sub);                   // this wave's first tap
    asm volatile("s_waitcnt vmcnt(0)" ::: "memory");
    __builtin_amdgcn_s_barrier();            // everyone's halo parts landed
    for (int it = 0; it < 25; ++it) {
      int t0 = it + off;     if (t0 >= 25) t0 -= 25;   // this wave's current tap
      int t1 = it + 1 + off; if (t1 >= 25) t1 -= 25;   // next (dead clamp at it==24)
      // ---- A halo reads FIRST (independent of B's vmcnt) ----
      const int dy = t0 / 5, dx = t0 - dy * 5;
      const int hcol = (l & 15) + dx;
      const int slot3 = kc8 ^ (hcol & 7);
      const int abase = (dy * 20 + hcol) * 64 + slot3 * 8;
      f16x8 avh[8], avl[8];
#pragma unroll
      for (int fm = 0; fm < 8; ++fm) {
        avh[fm] = *(const f16x8*)&haloh[abase + fm * 1280];
        avl[fm] = *(const f16x8*)&halol[abase + fm * 1280];
      }
      stageB(cur ^ 1, t1, sub);                         // issue next B (4 gload16)
      asm volatile("s_waitcnt vmcnt(4)" ::: "memory");  // MY cur-buf B landed
      const f16* bufB = (const f16*)(smem + 61440 + w * 8192 + cur * 4096);
      f16x8 bvh[2], bvl[2];
      bvh[0] = *(const f16x8*)&bufB[rB0 + rcB];
      bvh[1] = *(const f16x8*)&bufB[rB1 + rcB];
      bvl[0] = *(const f16x8*)&bufB[1024 + rB0 + rcB];
      bvl[1] = *(const f16x8*)&bufB[1024 + rB1 + rcB];
      __builtin_amdgcn_s_setprio(1);
#pragma unroll
      for (int fm = 0; fm < 8; ++fm) {
#pragma unroll
        for (int fn = 0; fn < 2; ++fn) {
          acc[fm][fn] =
              __builtin_amdgcn_mfma_f32_16x16x32_f16(avh[fm], bvh[fn], acc[fm][fn], 0, 0, 0);
          acc[fm][fn] =
              __builtin_amdgcn_mfma_f32_16x16x32_f16(avl[fm], bvh[fn], acc[fm][fn], 0, 0, 0);
          acc[fm][fn] =
              __builtin_amdgcn_mfma_f32_16x16x32_f16(avh[fm], bvl[fn], acc[fm][fn], 0, 0, 0);
        }
      }
      __builtin_amdgcn_s_setprio(0);
      cur ^= 1;
    }
  }

  asm volatile("s_waitcnt vmcnt(0)" ::: "memory");  // drain dead tail stages
  __builtin_amdgcn_s_barrier();                     // before macc overlay

  // ---- merge K-halves: h=1 writes acc to LDS (lane-major, conflict-free), h=0 adds ----
  if (h == 1) {
#pragma unroll
    for (int fm = 0; fm < 8; ++fm)
#pragma unroll
      for (int fn = 0; fn < 2; ++fn)
#pragma unroll
        for (int j = 0; j < 4; ++j)
          macc[ns * 4096 + ((fm * 2 + fn) * 4 + j) * 64 + l] = acc[fm][fn][j];
  }
  __syncthreads();
  if (h == 0) {
#pragma unroll
    for (int fm = 0; fm < 8; ++fm)
#pragma unroll
      for (int fn = 0; fn < 2; ++fn)
#pragma unroll
        for (int j = 0; j < 4; ++j)
          acc[fm][fn][j] += macc[ns * 4096 + ((fm * 2 + fn) * 4 + j) * 64 + l];

    // LSTM epilogue (h=0 waves only): gates of channel ch in 4 adjacent lanes.
#pragma unroll
    for (int fn = 0; fn < 2; ++fn) {
      const int col = ni * 128 + ns * 32 + fn * 16 + (l & 15);
      const float bias = bp[col];
      const int ch = col >> 2;
#pragma unroll
      for (int fm = 0; fm < 8; ++fm) {
#pragma unroll
        for (int j = 0; j < 4; ++j) {
          const float v = acc[fm][fn][j] + bias;
          const float t1 = __shfl_xor(v, 1);
          const float t2 = __shfl_xor(v, 2);
          const float t3 = __shfl_xor(t1, 2);
          if ((l & 3) == 0) {  // lane's col = i-gate; t1=f, t2=c_g, t3=o
            const int m = mi * 128 + fm * 16 + ((l >> 4) << 2) + j;
            const int cidx = m * HID + ch;
            const float cold = cst[cidx];
            const float cn = fsig(t1) * cold + fsig(v) * ftanh(t2);
            cst[cidx] = cn;
            const float hh_ = fsig(t3) * ftanh(cn);
            const int b = m >> 8, y = (m >> 4) & 15, x = m & 15;
            const int pidx = ((b * PADW + y + 2) * PADW + (x + 2)) * HID + ch;
            const f16 hv = (f16)hh_;
            Hnh[pidx] = hv;
            Hnl[pidx] = (f16)(hh_ - (float)hv);
          }
        }
      }
    }
  }
}

// ---------------- Kernel B: 3x3 out-conv (M=8192,N=64,K=1152) + LN + LeakyReLU + feedback ----
__global__ __launch_bounds__(256, 2) void kB(
    const f16* __restrict__ Hnh, const f16* __restrict__ Hnl,
    const f16* __restrict__ Cwh, const f16* __restrict__ Cwl,
    const float* __restrict__ cb, const float* __restrict__ gam,
    const float* __restrict__ bet, const float* __restrict__ tgt,
    const float* __restrict__ prob, float* __restrict__ outp,
    f16* __restrict__ Xph, f16* __restrict__ Xpl, int t) {
  __shared__ __align__(16) f16 sAh[2][32][64];
  __shared__ __align__(16) f16 sAl[2][32][64];
  __shared__ __align__(16) f16 sBh[2][64][64];
  __shared__ __align__(16) f16 sBl[2][64][64];
  __shared__ __align__(16) float yl[32][68];
  const int tid = threadIdx.x;
  const int l = tid & 63, w = tid >> 6;
  const int wm = w >> 1, wn = w & 1;
  const int mi = blockIdx.x;
  const int cof = ((l & 7) ^ (l >> 3)) * 8;

  const int rA = w * 8 + (l >> 3);
  const int mA = mi * 32 + rA;
  const int bA = mA >> 8, yA = (mA >> 4) & 15, xA = mA & 15;
  const int posA = (bA * PADW + yA + 2) * PADW + (xA + 2);
  int wBo[2];
#pragma unroll
  for (int i = 0; i < 2; ++i) wBo[i] = (w * 16 + i * 8 + (l >> 3)) * HID + cof;

  auto stage = [&](int bf, int it) {
    const int tap = it >> 1, sub = it & 1;
    const int dy = tap / 3, dx = tap - dy * 3;
    const int dt = (dy - 1) * PADW + (dx - 1);
    gload16(Hnh + (posA + dt) * HID + sub * 64 + cof, &sAh[bf][w * 8][0]);
    gload16(Hnl + (posA + dt) * HID + sub * 64 + cof, &sAl[bf][w * 8][0]);
    const int wo = tap * (64 * HID) + sub * 64;
#pragma unroll
    for (int i = 0; i < 2; ++i) {
      gload16(Cwh + wBo[i] + wo, &sBh[bf][w * 16 + i * 8][0]);
      gload16(Cwl + wBo[i] + wo, &sBl[bf][w * 16 + i * 8][0]);
    }
  };

  f32x4 acc[2] = {};

  stage(0, 0);
  __syncthreads();

  int buf = 0;
  for (int it = 0; it < 18; ++it) {  // 9 taps x 2 sub-blocks
    if (it < 17) stage(buf ^ 1, it + 1);
#pragma unroll
    for (int kk = 0; kk < 2; ++kk) {
      const int co = ((kk * 4 + (l >> 4)) ^ (l & 7)) * 8;
      const f16x8 ah = *(const f16x8*)&sAh[buf][wm * 16 + (l & 15)][co];
      const f16x8 al = *(const f16x8*)&sAl[buf][wm * 16 + (l & 15)][co];
#pragma unroll
      for (int fn = 0; fn < 2; ++fn) {
        const f16x8 bh = *(const f16x8*)&sBh[buf][wn * 32 + fn * 16 + (l & 15)][co];
        const f16x8 bl = *(const f16x8*)&sBl[buf][wn * 32 + fn * 16 + (l & 15)][co];
        acc[fn] = __builtin_amdgcn_mfma_f32_16x16x32_f16(ah, bh, acc[fn], 0, 0, 0);
        acc[fn] = __builtin_amdgcn_mfma_f32_16x16x32_f16(al, bh, acc[fn], 0, 0, 0);
        acc[fn] = __builtin_amdgcn_mfma_f32_16x16x32_f16(ah, bl, acc[fn], 0, 0, 0);
      }
    }
    __syncthreads();
    buf ^= 1;
  }

  // y -> LDS (+bias), then per-row LayerNorm over 64 channels
#pragma unroll
  for (int fn = 0; fn < 2; ++fn) {
    const int col = wn * 32 + fn * 16 + (l & 15);
    const float bias = cb[col];
#pragma unroll
    for (int j = 0; j < 4; ++j) yl[wm * 16 + (l >> 4) * 4 + j][col] = acc[fn][j] + bias;
  }
  __syncthreads();

  if (tid < 128) {
    const int row = tid >> 2, part = tid & 3;
    f32x4 vv[4];
    float s = 0.f, q = 0.f;
#pragma unroll
    for (int k2 = 0; k2 < 4; ++k2) {
      vv[k2] = *(const f32x4*)&yl[row][part * 16 + k2 * 4];
#pragma unroll
      for (int e = 0; e < 4; ++e) { const float f = vv[k2][e]; s += f; q += f * f; }
    }
    s += __shfl_xor(s, 1); q += __shfl_xor(q, 1);
    s += __shfl_xor(s, 2); q += __shfl_xor(q, 2);
    const float mean = s * 0.015625f;
    const float var = q * 0.015625f - mean * mean;
    const float rs = __builtin_amdgcn_rsqf(fmaxf(var, 0.f) + LNEPS);
    const int m = mi * 32 + row;
    const int b = m >> 8, pos = m & 255;
    const int py = pos >> 4, px = pos & 15;
    const long obase = (((long)b * TT + t) * 256 + pos) * COUT + part * 16;
    float* op = outp + obase;
    const float* tp = tgt + obase;
    const bool ar = (float)t < 100.f * prob[0];
    const int xoff = ((b * PADW + py + 2) * PADW + px + 2) * CIN + part * 16;
    f16x8 ph[2], pl[2];
#pragma unroll
    for (int k2 = 0; k2 < 4; ++k2) {
      f32x4 o4;
#pragma unroll
      for (int e = 0; e < 4; ++e) {
        const int c = part * 16 + k2 * 4 + e;
        float val = (vv[k2][e] - mean) * rs * gam[c] + bet[c];
        val = val >= 0.f ? val : ALPHA * val;
        o4[e] = val;
        const float nxt = ar ? val : tp[k2 * 4 + e];
        const f16 nh = (f16)nxt;
        const int i16 = k2 * 4 + e;
        ph[i16 >> 3][i16 & 7] = nh;
        pl[i16 >> 3][i16 & 7] = (f16)(nxt - (float)nh);
      }
      *(f32x4*)(op + k2 * 4) = o4;
    }
    *(f16x8*)(Xph + xoff) = ph[0];
    *(f16x8*)(Xph + xoff + 8) = ph[1];
    *(f16x8*)(Xpl + xoff) = pl[0];
    *(f16x8*)(Xpl + xoff + 8) = pl[1];
  }
}

// ---------------- init / weight conversion (hi+lo split) ----------------
__global__ void k_wcomb(const float* __restrict__ Wx, const float* __restrict__ Wh,
                        f16* __restrict__ Wch, f16* __restrict__ Wcl) {
  const int idx = blockIdx.x * 256 + threadIdx.x;  // [tap][n_new][c], 25*512*192
  if (idx >= 25 * 512 * 192) return;
  const int c = idx % 192, r = idx / 192;
  const int n = r % 512, tap = r / 512;
  const int ch = n >> 2, g = n & 3, no = g * 128 + ch;
  const float v = (c < 64) ? Wx[(tap * 64 + c) * 512 + no]
                           : Wh[(tap * 128 + (c - 64)) * 512 + no];
  const f16 vh = (f16)v;
  Wch[idx] = vh;
  Wcl[idx] = (f16)(v - (float)vh);
}
__global__ void k_wconv(const float* __restrict__ cw, f16* __restrict__ Cwh,
                        f16* __restrict__ Cwl) {
  const int idx = blockIdx.x * 256 + threadIdx.x;  // [tap][n][c], 9*64*128
  if (idx >= 9 * 64 * 128) return;
  const int c = idx % 128, r = idx / 128;
  const int n = r % 64, tap = r / 64;
  const float v = cw[(tap * 128 + c) * 64 + n];
  const f16 vh = (f16)v;
  Cwh[idx] = vh;
  Cwl[idx] = (f16)(v - (float)vh);
}
__global__ void k_bperm(const float* __restrict__ b, float* __restrict__ bp) {
  const int n = blockIdx.x * 256 + threadIdx.x;
  if (n < 512) bp[n] = b[(n & 3) * 128 + (n >> 2)];
}
__global__ void k_init(const float* __restrict__ x0, const float* __restrict__ h0,
                       const float* __restrict__ c0, f16* __restrict__ Xph,
                       f16* __restrict__ Xpl, f16* __restrict__ Hh, f16* __restrict__ Hl,
                       float* __restrict__ cst) {
  const int idx = blockIdx.x * 256 + threadIdx.x;
  if (idx < 32 * 256 * 64) {
    const int ch = idx & 63, m = idx >> 6;
    const int b = m >> 8, y = (m >> 4) & 15, x = m & 15;
    const int p = ((b * PADW + y + 2) * PADW + x + 2) * CIN + ch;
    const float v = x0[idx];
    const f16 vh = (f16)v;
    Xph[p] = vh;
    Xpl[p] = (f16)(v - (float)vh);
  } else if (idx < 32 * 256 * 64 + 32 * 256 * 128) {
    const int j = idx - 32 * 256 * 64;
    const int ch = j & 127, m = j >> 7;
    const int b = m >> 8, y = (m >> 4) & 15, x = m & 15;
    const int p = ((b * PADW + y + 2) * PADW + x + 2) * HID + ch;
    const float v = h0[j];
    const f16 vh = (f16)v;
    Hh[p] = vh;
    Hl[p] = (f16)(v - (float)vh);
  } else if (idx < 32 * 256 * 64 + 2 * 32 * 256 * 128) {
    const int j = idx - 32 * 256 * 64 - 32 * 256 * 128;
    cst[j] = c0[j];
  }
}

extern "C" void kernel_launch(void* const* d_in, const int* in_sizes, int n_in,
                              void* d_out, int out_size, void* d_ws, size_t ws_size,
                              hipStream_t stream) {
  (void)in_sizes; (void)n_in; (void)out_size; (void)ws_size;
  const float* x0  = (const float*)d_in[0];
  const float* h0  = (const float*)d_in[1];
  const float* c0  = (const float*)d_in[2];
  const float* tgt = (const float*)d_in[3];
  const float* pr  = (const float*)d_in[4];
  const float* Wx  = (const float*)d_in[5];
  const float* Wh  = (const float*)d_in[6];
  const float* bb  = (const float*)d_in[7];
  const float* cw  = (const float*)d_in[8];
  const float* cbv = (const float*)d_in[9];
  const float* gam = (const float*)d_in[10];
  const float* bet = (const float*)d_in[11];
  float* outp = (float*)d_out;
  char* ws = (char*)d_ws;
  f16*   Xph = (f16*)(ws + 0);            // 1,638,400 B (32x20x20x64)
  f16*   Xpl = (f16*)(ws + 1638400);      // 1,638,400 B
  f16*   Hh0 = (f16*)(ws + 3276800);      // 3,276,800 B (32x20x20x128)
  f16*   Hl0 = (f16*)(ws + 6553600);      // 3,276,800 B
  f16*   Hh1 = (f16*)(ws + 9830400);      // 3,276,800 B
  f16*   Hl1 = (f16*)(ws + 13107200);     // 3,276,800 B
  float* cst = (float*)(ws + 16384000);   // 4,194,304 B (32x256x128 f32)
  f16*   Wch = (f16*)(ws + 20578304);     // 4,915,200 B (25x512x192)
  f16*   Wcl = (f16*)(ws + 25493504);     // 4,915,200 B
  f16*   Cwh = (f16*)(ws + 30408704);     //   147,456 B (9x64x128)
  f16*   Cwl = (f16*)(ws + 30556160);     //   147,456 B
  float* bp  = (float*)(ws + 30703616);   //     2,048 B

  hipMemsetAsync(Xph, 0, 1638400, stream);
  hipMemsetAsync(Xpl, 0, 1638400, stream);
  hipMemsetAsync(Hh0, 0, 3276800, stream);
  hipMemsetAsync(Hl0, 0, 3276800, stream);
  hipMemsetAsync(Hh1, 0, 3276800, stream);
  hipMemsetAsync(Hl1, 0, 3276800, stream);
  k_wcomb<<<9600, 256, 0, stream>>>(Wx, Wh, Wch, Wcl);
  k_wconv<<<288, 256, 0, stream>>>(cw, Cwh, Cwl);
  k_bperm<<<2, 256, 0, stream>>>(bb, bp);
  k_init<<<10240, 256, 0, stream>>>(x0, h0, c0, Xph, Xpl, Hh0, Hl0, cst);

  for (int t = 0; t < TT; ++t) {
    f16* hch = (t & 1) ? Hh1 : Hh0;
    f16* hcl = (t & 1) ? Hl1 : Hl0;
    f16* hnh = (t & 1) ? Hh0 : Hh1;
    f16* hnl = (t & 1) ? Hl0 : Hl1;
    kA10<<<256, 512, 0, stream>>>(Xph, Xpl, hch, hcl, hnh, hnl, Wch, Wcl, bp, cst);
    kB<<<256, 256, 0, stream>>>(hnh, hnl, Cwh, Cwl, cbv, gam, bet, tgt, pr, outp, Xph, Xpl, t);
  }
}

// Round 15
// 12712.038 us; speedup vs baseline: 1.0490x; 1.0490x over previous
//
#include <hip/hip_runtime.h>

#define TT   100
#define PADW 20
#define HID  128
#define CIN  64
#define COUT 64
#define ALPHA 0.2f
#define LNEPS 1e-3f

typedef _Float16 f16;
typedef __attribute__((ext_vector_type(8))) _Float16 f16x8;
typedef __attribute__((ext_vector_type(4))) float f32x4;

__device__ __forceinline__ float fsig(float x) {
  return __builtin_amdgcn_rcpf(1.f + __builtin_amdgcn_exp2f(-1.44269504089f * x));
}
__device__ __forceinline__ float ftanh(float x) {
  return 1.f - 2.f * __builtin_amdgcn_rcpf(1.f + __builtin_amdgcn_exp2f(2.88539008178f * x));
}
__device__ __forceinline__ void gload16(const void* g, void* l) {
  __builtin_amdgcn_global_load_lds((const __attribute__((address_space(1))) void*)g,
                                   (__attribute__((address_space(3))) void*)l,
                                   16, 0, 0);
}

// ---------------- Kernel A: gate conv GEMM (M=8192,N=512,K=4800) + LSTM update ----------------
// EMPIRICAL OPTIMUM (R12): halo-in-LDS. The A-tile for all 25 taps of one 64-ch sub-block is
// one contiguous 12x20-pixel slab (30KB x hi/lo), staged ONCE per sub-block (3x/step); the 25
// tap-iters read shifted fragments from the read-only halo. Only B (L2-resident weights) is
// double-buffered per tap-iter -> the per-iter barrier waits only on 4 fast B loads.
// Halo swizzle: pixel-major 8x16B chunks, sigma=(hcol&7), store/read-canceling. K-split wave
// pairs (q, h) share output quadrant q (64x64), each computes K-half kk=h; LDS acc merge;
// h=0 waves run the gate-interleaved LSTM epilogue.
__global__ __launch_bounds__(512, 1) void kA8(
    const f16* __restrict__ Xh, const f16* __restrict__ Xl,
    const f16* __restrict__ Hch, const f16* __restrict__ Hcl,
    f16* __restrict__ Hnh, f16* __restrict__ Hnl,
    const f16* __restrict__ Wch, const f16* __restrict__ Wcl,
    const float* __restrict__ bp, float* __restrict__ cst) {
  __shared__ __align__(16) char smem[126976];
  f16* haloh = (f16*)(smem);             // 240 pixels x 64ch = 30720 B
  f16* halol = (f16*)(smem + 30720);     // 30720 B
  f16 (*sBh)[128][64] = (f16(*)[128][64])(smem + 61440);   // 2 x 16 KB
  f16 (*sBl)[128][64] = (f16(*)[128][64])(smem + 94208);   // 2 x 16 KB
  float* macc = (float*)smem;  // merge area (64 KB), overlaid after final barrier

  const int tid = threadIdx.x;
  const int l = tid & 63, w = tid >> 6;
  const int h = w & 1, q = w >> 1;          // K-half, quadrant
  const int qm = q >> 1, qn = q & 1;        // quadrant coords (2x2 of 64x64)
  // XCD-pinned decomposition: blocks dispatch round-robin over 8 XCDs (bid % 8).
  const int xcd = blockIdx.x & 7, slot = blockIdx.x >> 3;
  const int ni = xcd >> 1;                    // 2 XCDs per 128-col weight strip
  const int mi = ((xcd & 1) << 5) + slot;     // 0..63
  const int b_img = mi >> 1;                  // image index
  const int ybase = (mi & 1) * 8;             // padded-row base of this block's halo

  // B staging (identical to R10): wave w stages rows [w*16, w*16+16); chunk XOR by row&7
  const int cof = ((l & 7) ^ (l >> 3)) * 8;
  int wBo[2];
#pragma unroll
  for (int i = 0; i < 2; ++i) wBo[i] = (ni * 128 + w * 16 + i * 8 + (l >> 3)) * 192 + cof;

  // halo staging: 1920 slots of 16B per array; wave w covers gload indices w*4..w*4+3 (<30).
  // LDS(pix, slot3) = src(pix, slot3 ^ (hcol&7))  [store-side via pre-swizzled source]
  auto stageHalo = [&](int sub) {
#pragma unroll
    for (int i2 = 0; i2 < 4; ++i2) {
      const int gi = w * 4 + i2;
      if (gi < 30) {
        const int sabs = gi * 64 + l;            // this lane's slot
        const int pix = sabs >> 3, slot3 = sabs & 7;
        const int hrow = pix / 20, hcol = pix - hrow * 20;
        const int sc = slot3 ^ (hcol & 7);       // pre-swizzled source chunk
        const int gp = (b_img * PADW + ybase + hrow) * PADW + hcol;
        if (sub == 0) {
          gload16(Xh + gp * CIN + sc * 8, haloh + gi * 512);
          gload16(Xl + gp * CIN + sc * 8, halol + gi * 512);
        } else {
          const int ho = (sub - 1) * 64 + sc * 8;
          gload16(Hch + gp * HID + ho, haloh + gi * 512);
          gload16(Hcl + gp * HID + ho, halol + gi * 512);
        }
      }
    }
  };
  auto stageB = [&](int bf, int tap, int sub) {  // 4 gload16 per wave
    const int wo = tap * (512 * 192) + sub * 64;
#pragma unroll
    for (int i = 0; i < 2; ++i) {
      gload16(Wch + wBo[i] + wo, &sBh[bf][w * 16 + i * 8][0]);
      gload16(Wcl + wBo[i] + wo, &sBl[bf][w * 16 + i * 8][0]);
    }
  };

  f32x4 acc[4][4] = {};

  stageHalo(0);
  stageB(0, 0, 0);
  __syncthreads();

  const int kc8 = h * 4 + (l >> 4);                 // this wave's canonical k-chunk (of 8)
  const int co = (kc8 ^ (l & 7)) * 8;               // B swizzled read chunk (row&7 = l&7)

  int bufb = 0;
  for (int sub = 0; sub < 3; ++sub) {
    if (sub) {
      stageHalo(sub);       // prev sub's reads retired at last iter's barrier
      __syncthreads();      // drain halo (+staged-ahead B)
    }
    for (int tap = 0; tap < 25; ++tap) {
      // stage next B (next tap, or next sub's tap 0)
      if (tap + 1 < 25) stageB(bufb ^ 1, tap + 1, sub);
      else if (sub + 1 < 3) stageB(bufb ^ 1, 0, sub + 1);
      const int dy = tap / 5, dx = tap - dy * 5;
      const int hcol = (l & 15) + dx;
      const int slot3 = kc8 ^ (hcol & 7);
      const int aoff0 = ((qm * 4 + dy) * 20 + hcol) * 64 + slot3 * 8;
      f16x8 avh[4], avl[4], bvh[4], bvl[4];
#pragma unroll
      for (int fm = 0; fm < 4; ++fm) {
        avh[fm] = *(const f16x8*)&haloh[aoff0 + fm * 1280];
        avl[fm] = *(const f16x8*)&halol[aoff0 + fm * 1280];
      }
#pragma unroll
      for (int fn = 0; fn < 4; ++fn) {
        bvh[fn] = *(const f16x8*)&sBh[bufb][qn * 64 + fn * 16 + (l & 15)][co];
        bvl[fn] = *(const f16x8*)&sBl[bufb][qn * 64 + fn * 16 + (l & 15)][co];
      }
#pragma unroll
      for (int fm = 0; fm < 4; ++fm)
#pragma unroll
        for (int fn = 0; fn < 4; ++fn) {
          acc[fm][fn] =
              __builtin_amdgcn_mfma_f32_16x16x32_f16(avh[fm], bvh[fn], acc[fm][fn], 0, 0, 0);
          acc[fm][fn] =
              __builtin_amdgcn_mfma_f32_16x16x32_f16(avl[fm], bvh[fn], acc[fm][fn], 0, 0, 0);
          acc[fm][fn] =
              __builtin_amdgcn_mfma_f32_16x16x32_f16(avh[fm], bvl[fn], acc[fm][fn], 0, 0, 0);
        }
      __syncthreads();  // drains B(next) [issued 1 iter ago, L2-fast]; reads retired
      bufb ^= 1;
    }
  }

  // ---- merge K-halves: h=1 writes acc to LDS (lane-major, conflict-free), h=0 adds ----
  if (h == 1) {
#pragma unroll
    for (int fm = 0; fm < 4; ++fm)
#pragma unroll
      for (int fn = 0; fn < 4; ++fn)
#pragma unroll
        for (int j = 0; j < 4; ++j)
          macc[q * 4096 + ((fm * 4 + fn) * 4 + j) * 64 + l] = acc[fm][fn][j];
  }
  __syncthreads();
  if (h == 0) {
#pragma unroll
    for (int fm = 0; fm < 4; ++fm)
#pragma unroll
      for (int fn = 0; fn < 4; ++fn)
#pragma unroll
        for (int j = 0; j < 4; ++j)
          acc[fm][fn][j] += macc[q * 4096 + ((fm * 4 + fn) * 4 + j) * 64 + l];

    // LSTM epilogue (h=0 waves only): gates of channel ch in 4 adjacent lanes.
#pragma unroll
    for (int fn = 0; fn < 4; ++fn) {
      const int col = ni * 128 + qn * 64 + fn * 16 + (l & 15);
      const float bias = bp[col];
      const int ch = col >> 2;
#pragma unroll
      for (int fm = 0; fm < 4; ++fm) {
#pragma unroll
        for (int j = 0; j < 4; ++j) {
          const float v = acc[fm][fn][j] + bias;
          const float t1 = __shfl_xor(v, 1);
          const float t2 = __shfl_xor(v, 2);
          const float t3 = __shfl_xor(t1, 2);
          if ((l & 3) == 0) {  // lane's col = i-gate; t1=f, t2=c_g, t3=o
            const int m = mi * 128 + qm * 64 + fm * 16 + ((l >> 4) << 2) + j;
            const int cidx = m * HID + ch;
            const float cold = cst[cidx];
            const float cn = fsig(t1) * cold + fsig(v) * ftanh(t2);
            cst[cidx] = cn;
            const float hh_ = fsig(t3) * ftanh(cn);
            const int b = m >> 8, y = (m >> 4) & 15, x = m & 15;
            const int pidx = ((b * PADW + y + 2) * PADW + (x + 2)) * HID + ch;
            const f16 hv = (f16)hh_;
            Hnh[pidx] = hv;
            Hnl[pidx] = (f16)(hh_ - (float)hv);
          }
        }
      }
    }
  }
}

// ---------------- Kernel B: 3x3 out-conv (M=8192,N=64,K=1152) + LN + LeakyReLU + feedback ----
__global__ __launch_bounds__(256, 2) void kB(
    const f16* __restrict__ Hnh, const f16* __restrict__ Hnl,
    const f16* __restrict__ Cwh, const f16* __restrict__ Cwl,
    const float* __restrict__ cb, const float* __restrict__ gam,
    const float* __restrict__ bet, const float* __restrict__ tgt,
    const float* __restrict__ prob, float* __restrict__ outp,
    f16* __restrict__ Xph, f16* __restrict__ Xpl, int t) {
  __shared__ __align__(16) f16 sAh[2][32][64];
  __shared__ __align__(16) f16 sAl[2][32][64];
  __shared__ __align__(16) f16 sBh[2][64][64];
  __shared__ __align__(16) f16 sBl[2][64][64];
  __shared__ __align__(16) float yl[32][68];
  const int tid = threadIdx.x;
  const int l = tid & 63, w = tid >> 6;
  const int wm = w >> 1, wn = w & 1;
  const int mi = blockIdx.x;
  const int cof = ((l & 7) ^ (l >> 3)) * 8;

  const int rA = w * 8 + (l >> 3);
  const int mA = mi * 32 + rA;
  const int bA = mA >> 8, yA = (mA >> 4) & 15, xA = mA & 15;
  const int posA = (bA * PADW + yA + 2) * PADW + (xA + 2);
  int wBo[2];
#pragma unroll
  for (int i = 0; i < 2; ++i) wBo[i] = (w * 16 + i * 8 + (l >> 3)) * HID + cof;

  auto stage = [&](int bf, int it) {
    const int tap = it >> 1, sub = it & 1;
    const int dy = tap / 3, dx = tap - dy * 3;
    const int dt = (dy - 1) * PADW + (dx - 1);
    gload16(Hnh + (posA + dt) * HID + sub * 64 + cof, &sAh[bf][w * 8][0]);
    gload16(Hnl + (posA + dt) * HID + sub * 64 + cof, &sAl[bf][w * 8][0]);
    const int wo = tap * (64 * HID) + sub * 64;
#pragma unroll
    for (int i = 0; i < 2; ++i) {
      gload16(Cwh + wBo[i] + wo, &sBh[bf][w * 16 + i * 8][0]);
      gload16(Cwl + wBo[i] + wo, &sBl[bf][w * 16 + i * 8][0]);
    }
  };

  f32x4 acc[2] = {};

  stage(0, 0);
  __syncthreads();

  int buf = 0;
  for (int it = 0; it < 18; ++it) {  // 9 taps x 2 sub-blocks
    if (it < 17) stage(buf ^ 1, it + 1);
#pragma unroll
    for (int kk = 0; kk < 2; ++kk) {
      const int co = ((kk * 4 + (l >> 4)) ^ (l & 7)) * 8;
      const f16x8 ah = *(const f16x8*)&sAh[buf][wm * 16 + (l & 15)][co];
      const f16x8 al = *(const f16x8*)&sAl[buf][wm * 16 + (l & 15)][co];
#pragma unroll
      for (int fn = 0; fn < 2; ++fn) {
        const f16x8 bh = *(const f16x8*)&sBh[buf][wn * 32 + fn * 16 + (l & 15)][co];
        const f16x8 bl = *(const f16x8*)&sBl[buf][wn * 32 + fn * 16 + (l & 15)][co];
        acc[fn] = __builtin_amdgcn_mfma_f32_16x16x32_f16(ah, bh, acc[fn], 0, 0, 0);
        acc[fn] = __builtin_amdgcn_mfma_f32_16x16x32_f16(al, bh, acc[fn], 0, 0, 0);
        acc[fn] = __builtin_amdgcn_mfma_f32_16x16x32_f16(ah, bl, acc[fn], 0, 0, 0);
      }
    }
    __syncthreads();
    buf ^= 1;
  }

  // y -> LDS (+bias), then per-row LayerNorm over 64 channels
#pragma unroll
  for (int fn = 0; fn < 2; ++fn) {
    const int col = wn * 32 + fn * 16 + (l & 15);
    const float bias = cb[col];
#pragma unroll
    for (int j = 0; j < 4; ++j) yl[wm * 16 + (l >> 4) * 4 + j][col] = acc[fn][j] + bias;
  }
  __syncthreads();

  if (tid < 128) {
    const int row = tid >> 2, part = tid & 3;
    f32x4 vv[4];
    float s = 0.f, q = 0.f;
#pragma unroll
    for (int k2 = 0; k2 < 4; ++k2) {
      vv[k2] = *(const f32x4*)&yl[row][part * 16 + k2 * 4];
#pragma unroll
      for (int e = 0; e < 4; ++e) { const float f = vv[k2][e]; s += f; q += f * f; }
    }
    s += __shfl_xor(s, 1); q += __shfl_xor(q, 1);
    s += __shfl_xor(s, 2); q += __shfl_xor(q, 2);
    const float mean = s * 0.015625f;
    const float var = q * 0.015625f - mean * mean;
    const float rs = __builtin_amdgcn_rsqf(fmaxf(var, 0.f) + LNEPS);
    const int m = mi * 32 + row;
    const int b = m >> 8, pos = m & 255;
    const int py = pos >> 4, px = pos & 15;
    const long obase = (((long)b * TT + t) * 256 + pos) * COUT + part * 16;
    float* op = outp + obase;
    const float* tp = tgt + obase;
    const bool ar = (float)t < 100.f * prob[0];
    const int xoff = ((b * PADW + py + 2) * PADW + px + 2) * CIN + part * 16;
    f16x8 ph[2], pl[2];
#pragma unroll
    for (int k2 = 0; k2 < 4; ++k2) {
      f32x4 o4;
#pragma unroll
      for (int e = 0; e < 4; ++e) {
        const int c = part * 16 + k2 * 4 + e;
        float val = (vv[k2][e] - mean) * rs * gam[c] + bet[c];
        val = val >= 0.f ? val : ALPHA * val;
        o4[e] = val;
        const float nxt = ar ? val : tp[k2 * 4 + e];
        const f16 nh = (f16)nxt;
        const int i16 = k2 * 4 + e;
        ph[i16 >> 3][i16 & 7] = nh;
        pl[i16 >> 3][i16 & 7] = (f16)(nxt - (float)nh);
      }
      *(f32x4*)(op + k2 * 4) = o4;
    }
    *(f16x8*)(Xph + xoff) = ph[0];
    *(f16x8*)(Xph + xoff + 8) = ph[1];
    *(f16x8*)(Xpl + xoff) = pl[0];
    *(f16x8*)(Xpl + xoff + 8) = pl[1];
  }
}

// ---------------- init / weight conversion (hi+lo split) ----------------
__global__ void k_wcomb(const float* __restrict__ Wx, const float* __restrict__ Wh,
                        f16* __restrict__ Wch, f16* __restrict__ Wcl) {
  const int idx = blockIdx.x * 256 + threadIdx.x;  // [tap][n_new][c], 25*512*192
  if (idx >= 25 * 512 * 192) return;
  const int c = idx % 192, r = idx / 192;
  const int n = r % 512, tap = r / 512;
  const int ch = n >> 2, g = n & 3, no = g * 128 + ch;
  const float v = (c < 64) ? Wx[(tap * 64 + c) * 512 + no]
                           : Wh[(tap * 128 + (c - 64)) * 512 + no];
  const f16 vh = (f16)v;
  Wch[idx] = vh;
  Wcl[idx] = (f16)(v - (float)vh);
}
__global__ void k_wconv(const float* __restrict__ cw, f16* __restrict__ Cwh,
                        f16* __restrict__ Cwl) {
  const int idx = blockIdx.x * 256 + threadIdx.x;  // [tap][n][c], 9*64*128
  if (idx >= 9 * 64 * 128) return;
  const int c = idx % 128, r = idx / 128;
  const int n = r % 64, tap = r / 64;
  const float v = cw[(tap * 128 + c) * 64 + n];
  const f16 vh = (f16)v;
  Cwh[idx] = vh;
  Cwl[idx] = (f16)(v - (float)vh);
}
__global__ void k_bperm(const float* __restrict__ b, float* __restrict__ bp) {
  const int n = blockIdx.x * 256 + threadIdx.x;
  if (n < 512) bp[n] = b[(n & 3) * 128 + (n >> 2)];
}
__global__ void k_init(const float* __restrict__ x0, const float* __restrict__ h0,
                       const float* __restrict__ c0, f16* __restrict__ Xph,
                       f16* __restrict__ Xpl, f16* __restrict__ Hh, f16* __restrict__ Hl,
                       float* __restrict__ cst) {
  const int idx = blockIdx.x * 256 + threadIdx.x;
  if (idx < 32 * 256 * 64) {
    const int ch = idx & 63, m = idx >> 6;
    const int b = m >> 8, y = (m >> 4) & 15, x = m & 15;
    const int p = ((b * PADW + y + 2) * PADW + x + 2) * CIN + ch;
    const float v = x0[idx];
    const f16 vh = (f16)v;
    Xph[p] = vh;
    Xpl[p] = (f16)(v - (float)vh);
  } else if (idx < 32 * 256 * 64 + 32 * 256 * 128) {
    const int j = idx - 32 * 256 * 64;
    const int ch = j & 127, m = j >> 7;
    const int b = m >> 8, y = (m >> 4) & 15, x = m & 15;
    const int p = ((b * PADW + y + 2) * PADW + x + 2) * HID + ch;
    const float v = h0[j];
    const f16 vh = (f16)v;
    Hh[p] = vh;
    Hl[p] = (f16)(v - (float)vh);
  } else if (idx < 32 * 256 * 64 + 2 * 32 * 256 * 128) {
    const int j = idx - 32 * 256 * 64 - 32 * 256 * 128;
    cst[j] = c0[j];
  }
}

extern "C" void kernel_launch(void* const* d_in, const int* in_sizes, int n_in,
                              void* d_out, int out_size, void* d_ws, size_t ws_size,
                              hipStream_t stream) {
  (void)in_sizes; (void)n_in; (void)out_size; (void)ws_size;
  const float* x0  = (const float*)d_in[0];
  const float* h0  = (const float*)d_in[1];
  const float* c0  = (const float*)d_in[2];
  const float* tgt = (const float*)d_in[3];
  const float* pr  = (const float*)d_in[4];
  const float* Wx  = (const float*)d_in[5];
  const float* Wh  = (const float*)d_in[6];
  const float* bb  = (const float*)d_in[7];
  const float* cw  = (const float*)d_in[8];
  const float* cbv = (const float*)d_in[9];
  const float* gam = (const float*)d_in[10];
  const float* bet = (const float*)d_in[11];
  float* outp = (float*)d_out;
  char* ws = (char*)d_ws;
  f16*   Xph = (f16*)(ws + 0);            // 1,638,400 B (32x20x20x64)
  f16*   Xpl = (f16*)(ws + 1638400);      // 1,638,400 B
  f16*   Hh0 = (f16*)(ws + 3276800);      // 3,276,800 B (32x20x20x128)
  f16*   Hl0 = (f16*)(ws + 6553600);      // 3,276,800 B
  f16*   Hh1 = (f16*)(ws + 9830400);      // 3,276,800 B
  f16*   Hl1 = (f16*)(ws + 13107200);     // 3,276,800 B
  float* cst = (float*)(ws + 16384000);   // 4,194,304 B (32x256x128 f32)
  f16*   Wch = (f16*)(ws + 20578304);     // 4,915,200 B (25x512x192)
  f16*   Wcl = (f16*)(ws + 25493504);     // 4,915,200 B
  f16*   Cwh = (f16*)(ws + 30408704);     //   147,456 B (9x64x128)
  f16*   Cwl = (f16*)(ws + 30556160);     //   147,456 B
  float* bp  = (float*)(ws + 30703616);   //     2,048 B

  hipMemsetAsync(Xph, 0, 1638400, stream);
  hipMemsetAsync(Xpl, 0, 1638400, stream);
  hipMemsetAsync(Hh0, 0, 3276800, stream);
  hipMemsetAsync(Hl0, 0, 3276800, stream);
  hipMemsetAsync(Hh1, 0, 3276800, stream);
  hipMemsetAsync(Hl1, 0, 3276800, stream);
  k_wcomb<<<9600, 256, 0, stream>>>(Wx, Wh, Wch, Wcl);
  k_wconv<<<288, 256, 0, stream>>>(cw, Cwh, Cwl);
  k_bperm<<<2, 256, 0, stream>>>(bb, bp);
  k_init<<<10240, 256, 0, stream>>>(x0, h0, c0, Xph, Xpl, Hh0, Hl0, cst);

  for (int t = 0; t < TT; ++t) {
    f16* hch = (t & 1) ? Hh1 : Hh0;
    f16* hcl = (t & 1) ? Hl1 : Hl0;
    f16* hnh = (t & 1) ? Hh0 : Hh1;
    f16* hnl = (t & 1) ? Hl0 : Hl1;
    kA8<<<256, 512, 0, stream>>>(Xph, Xpl, hch, hcl, hnh, hnl, Wch, Wcl, bp, cst);
    kB<<<256, 256, 0, stream>>>(hnh, hnl, Cwh, Cwl, cbv, gam, bet, tgt, pr, outp, Xph, Xpl, t);
  }
}